// Round 9
// baseline (210.282 us; speedup 1.0000x reference)
//
#include <hip/hip_runtime.h>
#include <hip/hip_bf16.h>

// Problem constants
#define B_ 8
#define S_ 4096
#define H_ 512

using short8 = __attribute__((ext_vector_type(8))) short;
using f32x4  = __attribute__((ext_vector_type(4))) float;

// ---------- helpers ----------
__device__ __forceinline__ float bf2f(unsigned u16) {
    return __uint_as_float(u16 << 16);
}
__device__ __forceinline__ unsigned pk2bf(float x, float y) {
    __hip_bfloat162 h = __float22bfloat162_rn(make_float2(x, y));  // v_cvt_pk_bf16_f32
    return *reinterpret_cast<unsigned*>(&h);
}
__device__ __forceinline__ float softplus_f(float x) {
    float sp = __logf(1.0f + __expf(x));
    return x > 15.0f ? x : sp;
}

// async global->LDS, 16B per lane; LDS dest = wave-uniform base + lane*16
typedef __attribute__((address_space(1))) void* gbl_ptr_t;
typedef __attribute__((address_space(3))) void* lds_ptr_t;
__device__ __forceinline__ void gload_lds16(const void* g, void* l) {
    __builtin_amdgcn_global_load_lds((gbl_ptr_t)g, (lds_ptr_t)l, 16, 0, 0);
}

// raw barrier (no vmcnt/lgkmcnt drain) with compiler memory fences
#define BAR() do { asm volatile("" ::: "memory"); \
                   __builtin_amdgcn_s_barrier(); \
                   asm volatile("" ::: "memory"); } while (0)

// ---------- Pass 1: one-shot fp32 -> bf16 conversion (round-8, contiguous) ----
#define ASZ4 4194304u   // A float4 count
#define TOT4 4325376u   // A + W float4 count

__global__ __launch_bounds__(256)
void convert_bf16(const float* __restrict__ A, const float* __restrict__ Wm,
                  uint2* __restrict__ dst) {
    for (unsigned i = blockIdx.x * 256u + threadIdx.x; i < TOT4; i += 2048u * 256u) {
        const float4* p = (i < ASZ4) ? ((const float4*)A) + i
                                     : ((const float4*)Wm) + (i - ASZ4);
        const float4 v = *p;
        uint2 o;
        o.x = pk2bf(v.x, v.y);
        o.y = pk2bf(v.z, v.w);
        dst[i] = o;
    }
}

// ---------- Pass 2: 256x256 bf16 GEMM, BK=32 2-slot ring, counted vmcnt ------
// Round-8 analysis: 128^2 tile stages 537 MB through L2 (A re-staged N/TN=8x,
// B M/TM=256x) -> ~1170 cyc/slice/CU of L2->LDS movement vs ~310 cyc of MFMA:
// the kernel was STAGING-BANDWIDTH-bound (why depth-3 and occupancy were both
// null). 256^2 tile halves staged bytes to 268 MB and per-CU staging (1 block,
// 32 KB/slice ~570 cyc) drops BELOW the MFMA critical path (2 waves/SIMD x 32
// MFMA x 19.4 cyc ~1240). LDS = 2 slots x (256x32) x 2 arrays = 64 KB static
// (proven safe in round 7; the 128 KB variants were rounds 2/3's crashes).
// 512 threads = 8 waves (2M x 4N), per-wave 128x64 out, acc[8][4] = 128 VGPR;
// ~200 total < 256 -> __launch_bounds__(512,2) (no forced-spill, cf round 5).
// Same counted-vmcnt ring: STAGE(g+1) before compute g, vmcnt(4), never 0
// until the tail. Swizzle s(row)=(row+(row>>2))&3 (invariant +16/+64/+128).
#define TM 256
#define TN 256
#define BK 32

__global__ __launch_bounds__(512, 2)
void gemm_softplus(const unsigned short* __restrict__ Ab,
                   const unsigned short* __restrict__ Wb,
                   const float* __restrict__ bias,
                   unsigned* __restrict__ QR) {
    __shared__ unsigned short As[2][8192];   // 2 slots x (256 rows x 32 bf16) = 32 KB
    __shared__ unsigned short Bs[2][8192];   // 32 KB   (total 64 KB static)

    // XCD-chunked swizzle: 512 blocks = 8 XCD * 64; the 4 blocks sharing an
    // A strip (same bm) are logical-consecutive -> one XCD.
    const int bid     = blockIdx.x;
    const int logical = (bid & 7) * 64 + (bid >> 3);
    const int bm = logical >> 2;     // 0..127
    const int bn = logical & 3;      // 0..3

    const int t      = threadIdx.x;
    const int wave   = t >> 6;       // 0..7
    const int lane   = t & 63;
    const int wave_m = wave >> 2;    // 0..1
    const int wave_n = wave & 3;     // 0..3
    const int wm  = wave_m * 128;
    const int wn  = wave_n * 64;
    const int l15 = lane & 15;
    const int l4  = lane >> 4;

    const int m0 = bm * TM;

    // ---- staging geometry (linear LDS dest, inverse-swizzled global source) ----
    // issue e (0,1) covers tile rows e*128 + wave*16 + (lane>>2); lane writes the
    // 16B granule (lane&3). s(row) mod-4 reduces to ((lane>>2)+(lane>>4))&3 for
    // every e/wave (e*128, wave*16 vanish mod 4 after the +row>>2 term).
    const int lr2  = lane >> 2;                        // 0..15
    const int s_st = (lr2 + (lane >> 4)) & 3;
    const int sg   = ((lane & 3) ^ s_st) * 8;          // source k offset (elems)
    const int row0 = wave * 16 + lr2;                  // tile row, issue 0 (0..127)
    // B tile row -> W row (256 rows): 32-row groups alternate q/r, 32 cols each:
    // n(row) = bn*128 + (row>>6)*32 + (row&31) + 512*((row>>5)&1).
    // Per wave (wn=wave_n*64): acc[.][j] j=0,1 are q cols h = bn*128+(wn>>1)+j*16+l15,
    // acc[.][j+2] the matching r cols (h+512) -> packed {q,r} epilogue preserved.
    // issue 1 (row+128): row>>6 += 2 -> n += 64; (row>>5)&1 unchanged.
    const int nr0 = bn * 128 + ((row0 >> 6) << 5) + (row0 & 31) + (((row0 >> 5) & 1) << 9);
    const unsigned short* agA0 = Ab + (size_t)(m0 + row0) * 512 + sg;
    const unsigned short* agA1 = agA0 + (size_t)128 * 512;   // issue 1: A rows +128
    const unsigned short* bgB0 = Wb + (size_t)nr0 * 512 + sg;
    const unsigned short* bgB1 = bgB0 + (size_t)64 * 512;    // issue 1: B cols +64
    const int sd = wave * 512;           // LDS dest (elems), wave-uniform; +4096 for e=1

    // ---- ds_read geometry (swizzled read matches staged content) ----
    // fragment rows are wm/wn + k*16 + l15; s(row) mod 4 = (l15 + (l15>>2)) & 3.
    const int s_rd = (l15 + (l15 >> 2)) & 3;
    const int gsw  = (l4 ^ s_rd) * 8;
    const int aoff = (wm + l15) * 32 + gsw;   // + i*512 per fragment (compile-time)
    const int boff = (wn + l15) * 32 + gsw;   // + j*512

    f32x4 acc[8][4] = {};

#define STAGE(s) do { \
    const int _sl = (s) & 1; const int _kc = (s) * BK; \
    gload_lds16(agA0 + _kc, &As[_sl][sd]); \
    gload_lds16(agA1 + _kc, &As[_sl][sd + 4096]); \
    gload_lds16(bgB0 + _kc, &Bs[_sl][sd]); \
    gload_lds16(bgB1 + _kc, &Bs[_sl][sd + 4096]); \
} while (0)

#define SLICE(g, VMN, DOSTG) do { \
    const unsigned short* _a = &As[(g) & 1][0]; \
    const unsigned short* _b = &Bs[(g) & 1][0]; \
    if (DOSTG) STAGE((g) + 1); \
    asm volatile("s_waitcnt vmcnt(" #VMN ")" ::: "memory"); \
    BAR(); \
    short8 af[8], bf[4]; \
    _Pragma("unroll") for (int j = 0; j < 4; ++j) \
        bf[j] = *(const short8*)(_b + boff + j * 512); \
    _Pragma("unroll") for (int i = 0; i < 8; ++i) \
        af[i] = *(const short8*)(_a + aoff + i * 512); \
    __builtin_amdgcn_s_setprio(1); \
    _Pragma("unroll") for (int i = 0; i < 8; ++i) \
    _Pragma("unroll") for (int j = 0; j < 4; ++j) \
        acc[i][j] = __builtin_amdgcn_mfma_f32_16x16x32_bf16(af[i], bf[j], acc[i][j], 0, 0, 0); \
    __builtin_amdgcn_s_setprio(0); \
    BAR(); \
} while (0)

    STAGE(0);                                   // 4 loads in flight
    for (int g = 0; g < 15; ++g) {
        SLICE(g, 4, 1);                         // stage g+1; wait slice g only
    }
    SLICE(15, 0, 0);                            // tail: full drain is free

#undef SLICE
#undef STAGE

    // epilogue: bias + softplus, packed {q,r} 4B stores
#pragma unroll
    for (int j = 0; j < 2; ++j) {
        const int h  = bn * 128 + (wn >> 1) + j * 16 + l15;  // 0..511
        const float bq = bias[h];
        const float br = bias[h + 512];
#pragma unroll
        for (int i = 0; i < 8; ++i) {
            const int mb = m0 + wm + i * 16 + l4 * 4;
#pragma unroll
            for (int r = 0; r < 4; ++r) {
                const float qv = softplus_f(acc[i][j][r] + bq);
                const float rv = softplus_f(acc[i][j + 2][r] + br);
                QR[(size_t)(mb + r) * 512 + h] = pk2bf(qv, rv);
            }
        }
    }
}

// ---------- Pass 3: chunked Kalman scan (unchanged from rounds 4-8) ----------
#define CHUNK 128
#define WARM 64

__global__ __launch_bounds__(256, 2)
void kalman_scan(const float* __restrict__ z,
                 const unsigned* __restrict__ QR,
                 float* __restrict__ out) {
    const int t     = threadIdx.x;
    const int hb    = blockIdx.x & 1;
    const int b     = (blockIdx.x >> 1) & 7;
    const int chunk = blockIdx.x >> 4;          // 0..31
    const int h     = hb * 256 + t;             // 0..511
    const int s0    = chunk << 7;               // chunk*128
    const int sw    = (chunk == 0) ? 0 : (s0 - WARM);
    const size_t base = ((size_t)(b * S_ + sw)) * 512 + h;

    const float*    zp  = z + base;             // stride 512 floats / step
    const unsigned* qrp = (const unsigned*)QR + base;
    float*          op  = out + base;

    const int ng    = ((s0 + CHUNK) - sw) >> 3;   // 16 (chunk 0) or 24
    const int skipg = (s0 - sw) >> 3;             // 0 or 8

    float    Z0[8], Z1[8], Z2[8], Z3[8], Z4[8], Z5[8], Z6[8], Z7[8];
    unsigned Q0[8], Q1[8], Q2[8], Q3[8], Q4[8], Q5[8], Q6[8], Q7[8];

#define LOADG(g, Zb, Qb) { const int _o = (g) * 8;                          \
    _Pragma("unroll") for (int u = 0; u < 8; ++u) {                         \
        Zb[u] = zp[(size_t)(_o + u) * 512]; Qb[u] = qrp[(size_t)(_o + u) * 512]; } }

#define COMP(g, Zb, Qb) { const int _o = (g) * 8; const bool _st = (g) >= skipg; \
    _Pragma("unroll") for (int u = 0; u < 8; ++u) {                         \
        const float q  = bf2f(Qb[u] & 0xffffu);                             \
        const float r  = bf2f(Qb[u] >> 16);                                 \
        const float Pp = P + q, rr = r + 1e-6f;                             \
        const float K  = Pp * __builtin_amdgcn_rcpf(Pp + rr);               \
        state = fmaf(K, Zb[u] - state, state); P = rr * K;                  \
        if (_st) op[(size_t)(_o + u) * 512] = state; } }

    LOADG(0, Z0, Q0); LOADG(1, Z1, Q1); LOADG(2, Z2, Q2); LOADG(3, Z3, Q3);

    float state = Z0[0];   // state init = z[sw]
    float P = 0.1f;

    for (int g = 0; g < ng; g += 8) {
        if (g + 4  < ng) LOADG(g + 4,  Z4, Q4); COMP(g,     Z0, Q0);
        if (g + 5  < ng) LOADG(g + 5,  Z5, Q5); COMP(g + 1, Z1, Q1);
        if (g + 6  < ng) LOADG(g + 6,  Z6, Q6); COMP(g + 2, Z2, Q2);
        if (g + 7  < ng) LOADG(g + 7,  Z7, Q7); COMP(g + 3, Z3, Q3);
        if (g + 8  < ng) LOADG(g + 8,  Z0, Q0); COMP(g + 4, Z4, Q4);
        if (g + 9  < ng) LOADG(g + 9,  Z1, Q1); COMP(g + 5, Z5, Q5);
        if (g + 10 < ng) LOADG(g + 10, Z2, Q2); COMP(g + 6, Z6, Q6);
        if (g + 11 < ng) LOADG(g + 11, Z3, Q3); COMP(g + 7, Z7, Q7);
    }
#undef LOADG
#undef COMP
}

extern "C" void kernel_launch(void* const* d_in, const int* in_sizes, int n_in,
                              void* d_out, int out_size, void* d_ws, size_t ws_size,
                              hipStream_t stream) {
    const float* lstm = (const float*)d_in[0];   // (8,4096,512) fp32
    const float* Wm   = (const float*)d_in[1];   // (1024,512)  fp32
    const float* bias = (const float*)d_in[2];   // (1024,)     fp32

    unsigned* QRw = (unsigned*)d_ws;             // packed {q,r} bf16x2, 64 MB

    // d_out (64 MB) is dead until the scan writes it -> bf16 scratch:
    // Ab = 32 MB at offset 0, Wb = 1 MB at offset 32 MB (contiguous).
    unsigned short* Abf = (unsigned short*)d_out;
    unsigned short* Wbf = (unsigned short*)((char*)d_out + (32u << 20));

    hipLaunchKernelGGL(convert_bf16, dim3(2048), dim3(256), 0, stream,
                       lstm, Wm, (uint2*)Abf);

    // 128 M-tiles x 4 N-tiles = 512 blocks of 512 threads (1 block/CU, 2 rounds)
    hipLaunchKernelGGL(gemm_softplus, dim3(512), dim3(512), 0, stream,
                       Abf, Wbf, bias, QRw);

    // 2 h-halves * 8 batches * 32 chunks = 512 blocks of 256 threads (2/CU)
    hipLaunchKernelGGL(kalman_scan, dim3(512), dim3(256), 0, stream,
                       lstm, QRw, (float*)d_out);
}

// Round 10
// 197.845 us; speedup vs baseline: 1.0629x; 1.0629x over previous
//
#include <hip/hip_runtime.h>
#include <hip/hip_bf16.h>

// Problem constants
#define B_ 8
#define S_ 4096
#define H_ 512

using short8 = __attribute__((ext_vector_type(8))) short;
using f32x4  = __attribute__((ext_vector_type(4))) float;

// ---------- helpers ----------
__device__ __forceinline__ float bf2f(unsigned u16) {
    return __uint_as_float(u16 << 16);
}
__device__ __forceinline__ unsigned pk2bf(float x, float y) {
    __hip_bfloat162 h = __float22bfloat162_rn(make_float2(x, y));  // v_cvt_pk_bf16_f32
    return *reinterpret_cast<unsigned*>(&h);
}
__device__ __forceinline__ float softplus_f(float x) {
    float sp = __logf(1.0f + __expf(x));
    return x > 15.0f ? x : sp;
}

// async global->LDS, 16B per lane; LDS dest = wave-uniform base + lane*16
typedef __attribute__((address_space(1))) void* gbl_ptr_t;
typedef __attribute__((address_space(3))) void* lds_ptr_t;
__device__ __forceinline__ void gload_lds16(const void* g, void* l) {
    __builtin_amdgcn_global_load_lds((gbl_ptr_t)g, (lds_ptr_t)l, 16, 0, 0);
}

// raw barrier (no vmcnt/lgkmcnt drain) with compiler memory fences
#define BAR() do { asm volatile("" ::: "memory"); \
                   __builtin_amdgcn_s_barrier(); \
                   asm volatile("" ::: "memory"); } while (0)

// ---------- Pass 1: one-shot fp32 -> bf16 conversion (round-8, contiguous) ----
#define ASZ4 4194304u   // A float4 count
#define TOT4 4325376u   // A + W float4 count

__global__ __launch_bounds__(256)
void convert_bf16(const float* __restrict__ A, const float* __restrict__ Wm,
                  uint2* __restrict__ dst) {
    for (unsigned i = blockIdx.x * 256u + threadIdx.x; i < TOT4; i += 2048u * 256u) {
        const float4* p = (i < ASZ4) ? ((const float4*)A) + i
                                     : ((const float4*)Wm) + (i - ASZ4);
        const float4 v = *p;
        uint2 o;
        o.x = pk2bf(v.x, v.y);
        o.y = pk2bf(v.z, v.w);
        dst[i] = o;
    }
}

// ---------- Pass 2: 256x256 bf16 GEMM, m201-style 4-phase/K-tile schedule ----
// Every prior variant was a 2-phase structure (~580 TF documented ceiling;
// m233: stage+vmcnt+barrier = 72% of critical path). This is the T3+T4 port:
// KT=64 K-tiles, 2 LDS buffers x 2 k-halves, per-tile phases
//   p0: issue stage(t+1,kh0); vmcnt(8); bar; read B(ks0)+A(0..3,ks0); 16 MFMA
//   p1: read A(4..7,ks0); 16 MFMA                      (no barrier, no issue)
//   p2: issue stage(t+1,kh1); vmcnt(8); bar; read B(ks1)+A(0..3,ks1); 16 MFMA
//   p3: read A(4..7,ks1); 16 MFMA
//   tile-start barrier licenses overwriting the other buffer.
// => 64 MFMA per 3 barriers (vs 16 per 2); vmcnt counted (8), never 0 until
// the tail; 8-12 loads in flight per wave (ledger verified).
// LDS layout is k-half-major [buf][kh][256 rows][32 elems] (row stride 64 B)
// so each wave's 4-load stage lands contiguously (gload_lds requirement).
// Swizzle: LDS granule-slot g holds source k-granule g ^ ((row>>1)&3);
// read side: slot = l4 ^ ((l15>>1)&3) (uniform per lane, all strides
// compile-time). Bank check: 16 lanes/l4-group spread over 8 distinct 16B
// positions -> 2-way aliasing = free (m136).
// 128 KB LDS is DYNAMIC (extern __shared__ + hipFuncSetAttribute); the
// rounds-2/3 crashes were 128 KB *static* (> 64 KB static limit).
#define TM 256
#define TN 256
#define KT 64

__global__ __launch_bounds__(512, 2)
void gemm_softplus(const unsigned short* __restrict__ Ab,
                   const unsigned short* __restrict__ Wb,
                   const float* __restrict__ bias,
                   unsigned* __restrict__ QR) {
    extern __shared__ __align__(16) unsigned short smem[];
    unsigned short* Asm = smem;           // [2][2][8192] elems = 64 KB
    unsigned short* Bsm = smem + 32768;   // [2][2][8192] elems = 64 KB

    // XCD-chunked swizzle: 512 blocks = 8 XCD * 64; 4 logical-consecutive
    // blocks share bm (A strip) -> one XCD (r9 measured FETCH 24.7 MB).
    const int bid     = blockIdx.x;
    const int logical = (bid & 7) * 64 + (bid >> 3);
    const int bm = logical >> 2;     // 0..127
    const int bn = logical & 3;      // 0..3

    const int t      = threadIdx.x;
    const int wave   = t >> 6;       // 0..7
    const int lane   = t & 63;
    const int wave_m = wave >> 2;    // 0..1
    const int wave_n = wave & 3;     // 0..3
    const int wm  = wave_m * 128;
    const int wn  = wave_n * 64;
    const int l15 = lane & 15;
    const int l4  = lane >> 4;

    const int m0 = bm * TM;

    // ---- staging geometry ----
    // stage(t,kh), issue e in {0,1}: wave w covers rows e*128 + w*16 + q
    // (q = lane>>2); lane writes 16B granule-slot g = lane&3 of its row's
    // k-half; source granule = g ^ ((q>>1)&3)  (row>>1 == q>>1 mod 4: row =
    // e*128 + w*16 + q, and e*128, w*16 vanish mod 8 after >>1 ... mod 4).
    const int q_  = lane >> 2;                       // 0..15
    const int g_  = lane & 3;
    const int sgo = (g_ ^ ((q_ >> 1) & 3)) * 8;      // source k offset (elems)
    const int row0 = wave * 16 + q_;                 // issue-0 row (0..127)
    // B tile row -> W row (256 rows, 32-row q/r groups; r9-verified):
    // n(row) = bn*128 + (row>>6)*32 + (row&31) + 512*((row>>5)&1)
    const int nr0 = bn * 128 + ((row0 >> 6) << 5) + (row0 & 31) + (((row0 >> 5) & 1) << 9);
    const unsigned short* agA0 = Ab + (size_t)(m0 + row0) * 512 + sgo;
    const unsigned short* agA1 = agA0 + (size_t)128 * 512;   // e=1: A rows +128
    const unsigned short* bgB0 = Wb + (size_t)nr0 * 512 + sgo;
    const unsigned short* bgB1 = bgB0 + (size_t)64 * 512;    // e=1: n(row+128)=n+64
    const int sdw = wave * 512;    // LDS dest elems within [kh] block; +4096 for e=1

    // ---- ds_read geometry ----
    // fragment row r = (wm|wn) + i*16 + l15 -> (r>>1)&3 == (l15>>1)&3.
    const int gsw  = (l4 ^ ((l15 >> 1) & 3)) * 8;
    const int aoff = (wm + l15) * 32 + gsw;   // + i*512 ; + ks*8192 ; + buf*16384
    const int boff = (wn + l15) * 32 + gsw;   // + j*512

    f32x4 acc[8][4] = {};

#define STAGE(tt, kh) do { \
    const int _kc = (tt) * KT + (kh) * 32; \
    const int _db = ((tt) & 1) * 16384 + (kh) * 8192; \
    gload_lds16(agA0 + _kc, Asm + _db + sdw); \
    gload_lds16(agA1 + _kc, Asm + _db + sdw + 4096); \
    gload_lds16(bgB0 + _kc, Bsm + _db + sdw); \
    gload_lds16(bgB1 + _kc, Bsm + _db + sdw + 4096); \
} while (0)

#define MMA16(ibase) do { \
    __builtin_amdgcn_s_setprio(1); \
    _Pragma("unroll") for (int ii = 0; ii < 4; ++ii) \
    _Pragma("unroll") for (int jj = 0; jj < 4; ++jj) \
        acc[(ibase) + ii][jj] = __builtin_amdgcn_mfma_f32_16x16x32_bf16( \
            af[ii], bf[jj], acc[(ibase) + ii][jj], 0, 0, 0); \
    __builtin_amdgcn_s_setprio(0); \
} while (0)

#define TILE(tt, VM0, VM2, DOSTG) do { \
    const unsigned short* _a = Asm + ((tt) & 1) * 16384; \
    const unsigned short* _b = Bsm + ((tt) & 1) * 16384; \
    short8 af[4], bf[4]; \
    BAR();                               /* tile-start: prev-tile reads done */ \
    if (DOSTG) STAGE((tt) + 1, 0); \
    asm volatile("s_waitcnt vmcnt(" #VM0 ")" ::: "memory"); \
    BAR();                               /* (tt,kh0) landed for all waves */ \
    _Pragma("unroll") for (int jj = 0; jj < 4; ++jj) \
        bf[jj] = *(const short8*)(_b + boff + jj * 512); \
    _Pragma("unroll") for (int ii = 0; ii < 4; ++ii) \
        af[ii] = *(const short8*)(_a + aoff + ii * 512); \
    MMA16(0); \
    _Pragma("unroll") for (int ii = 0; ii < 4; ++ii) \
        af[ii] = *(const short8*)(_a + aoff + (ii + 4) * 512); \
    MMA16(4); \
    if (DOSTG) STAGE((tt) + 1, 1); \
    asm volatile("s_waitcnt vmcnt(" #VM2 ")" ::: "memory"); \
    BAR();                               /* (tt,kh1) landed */ \
    _Pragma("unroll") for (int jj = 0; jj < 4; ++jj) \
        bf[jj] = *(const short8*)(_b + 8192 + boff + jj * 512); \
    _Pragma("unroll") for (int ii = 0; ii < 4; ++ii) \
        af[ii] = *(const short8*)(_a + 8192 + aoff + ii * 512); \
    MMA16(0); \
    _Pragma("unroll") for (int ii = 0; ii < 4; ++ii) \
        af[ii] = *(const short8*)(_a + 8192 + aoff + (ii + 4) * 512); \
    MMA16(4); \
} while (0)

    // prologue: tile 0's two k-halves (8 loads in flight per wave)
    STAGE(0, 0); STAGE(0, 1);

    // steady state: tiles 0..6, issuing t+1, vmcnt(8) (retires exactly the
    // consumed k-half; 8-12 outstanding, never 0)
    for (int tt = 0; tt < 7; ++tt) TILE(tt, 8, 8, 1);
    // tail: tile 7, drain 8 -> 4 -> 0
    TILE(7, 4, 0, 0);

#undef TILE
#undef MMA16
#undef STAGE

    // epilogue (r9-verified): bias + softplus, packed {q,r} 4B stores
#pragma unroll
    for (int j = 0; j < 2; ++j) {
        const int h  = bn * 128 + (wn >> 1) + j * 16 + l15;  // 0..511
        const float bq = bias[h];
        const float br = bias[h + 512];
#pragma unroll
        for (int i = 0; i < 8; ++i) {
            const int mb = m0 + wm + i * 16 + l4 * 4;
#pragma unroll
            for (int r = 0; r < 4; ++r) {
                const float qv = softplus_f(acc[i][j][r] + bq);
                const float rv = softplus_f(acc[i][j + 2][r] + br);
                QR[(size_t)(mb + r) * 512 + h] = pk2bf(qv, rv);
            }
        }
    }
}

// ---------- Pass 3: chunked Kalman scan (unchanged from rounds 4-9) ----------
#define CHUNK 128
#define WARM 64

__global__ __launch_bounds__(256, 2)
void kalman_scan(const float* __restrict__ z,
                 const unsigned* __restrict__ QR,
                 float* __restrict__ out) {
    const int t     = threadIdx.x;
    const int hb    = blockIdx.x & 1;
    const int b     = (blockIdx.x >> 1) & 7;
    const int chunk = blockIdx.x >> 4;          // 0..31
    const int h     = hb * 256 + t;             // 0..511
    const int s0    = chunk << 7;               // chunk*128
    const int sw    = (chunk == 0) ? 0 : (s0 - WARM);
    const size_t base = ((size_t)(b * S_ + sw)) * 512 + h;

    const float*    zp  = z + base;             // stride 512 floats / step
    const unsigned* qrp = (const unsigned*)QR + base;
    float*          op  = out + base;

    const int ng    = ((s0 + CHUNK) - sw) >> 3;   // 16 (chunk 0) or 24
    const int skipg = (s0 - sw) >> 3;             // 0 or 8

    float    Z0[8], Z1[8], Z2[8], Z3[8], Z4[8], Z5[8], Z6[8], Z7[8];
    unsigned Q0[8], Q1[8], Q2[8], Q3[8], Q4[8], Q5[8], Q6[8], Q7[8];

#define LOADG(g, Zb, Qb) { const int _o = (g) * 8;                          \
    _Pragma("unroll") for (int u = 0; u < 8; ++u) {                         \
        Zb[u] = zp[(size_t)(_o + u) * 512]; Qb[u] = qrp[(size_t)(_o + u) * 512]; } }

#define COMP(g, Zb, Qb) { const int _o = (g) * 8; const bool _st = (g) >= skipg; \
    _Pragma("unroll") for (int u = 0; u < 8; ++u) {                         \
        const float q  = bf2f(Qb[u] & 0xffffu);                             \
        const float r  = bf2f(Qb[u] >> 16);                                 \
        const float Pp = P + q, rr = r + 1e-6f;                             \
        const float K  = Pp * __builtin_amdgcn_rcpf(Pp + rr);               \
        state = fmaf(K, Zb[u] - state, state); P = rr * K;                  \
        if (_st) op[(size_t)(_o + u) * 512] = state; } }

    LOADG(0, Z0, Q0); LOADG(1, Z1, Q1); LOADG(2, Z2, Q2); LOADG(3, Z3, Q3);

    float state = Z0[0];   // state init = z[sw]
    float P = 0.1f;

    for (int g = 0; g < ng; g += 8) {
        if (g + 4  < ng) LOADG(g + 4,  Z4, Q4); COMP(g,     Z0, Q0);
        if (g + 5  < ng) LOADG(g + 5,  Z5, Q5); COMP(g + 1, Z1, Q1);
        if (g + 6  < ng) LOADG(g + 6,  Z6, Q6); COMP(g + 2, Z2, Q2);
        if (g + 7  < ng) LOADG(g + 7,  Z7, Q7); COMP(g + 3, Z3, Q3);
        if (g + 8  < ng) LOADG(g + 8,  Z0, Q0); COMP(g + 4, Z4, Q4);
        if (g + 9  < ng) LOADG(g + 9,  Z1, Q1); COMP(g + 5, Z5, Q5);
        if (g + 10 < ng) LOADG(g + 10, Z2, Q2); COMP(g + 6, Z6, Q6);
        if (g + 11 < ng) LOADG(g + 11, Z3, Q3); COMP(g + 7, Z7, Q7);
    }
#undef LOADG
#undef COMP
}

extern "C" void kernel_launch(void* const* d_in, const int* in_sizes, int n_in,
                              void* d_out, int out_size, void* d_ws, size_t ws_size,
                              hipStream_t stream) {
    const float* lstm = (const float*)d_in[0];   // (8,4096,512) fp32
    const float* Wm   = (const float*)d_in[1];   // (1024,512)  fp32
    const float* bias = (const float*)d_in[2];   // (1024,)     fp32

    unsigned* QRw = (unsigned*)d_ws;             // packed {q,r} bf16x2, 64 MB

    // d_out (64 MB) is dead until the scan writes it -> bf16 scratch:
    // Ab = 32 MB at offset 0, Wb = 1 MB at offset 32 MB (contiguous).
    unsigned short* Abf = (unsigned short*)d_out;
    unsigned short* Wbf = (unsigned short*)((char*)d_out + (32u << 20));

    // enable 128 KB dynamic LDS for the GEMM (host-side, graph-capture-safe;
    // do it once per process)
    static bool lds_set = false;
    if (!lds_set) {
        hipFuncSetAttribute(reinterpret_cast<const void*>(&gemm_softplus),
                            hipFuncAttributeMaxDynamicSharedMemorySize, 131072);
        lds_set = true;
    }

    hipLaunchKernelGGL(convert_bf16, dim3(2048), dim3(256), 0, stream,
                       lstm, Wm, (uint2*)Abf);

    // 128 M-tiles x 4 N-tiles = 512 blocks of 512 threads, 128 KB dynamic LDS
    hipLaunchKernelGGL(gemm_softplus, dim3(512), dim3(512), 131072, stream,
                       Abf, Wbf, bias, QRw);

    // 2 h-halves * 8 batches * 32 chunks = 512 blocks of 256 threads (2/CU)
    hipLaunchKernelGGL(kalman_scan, dim3(512), dim3(256), 0, stream,
                       lstm, QRw, (float*)d_out);
}

// Round 11
// 195.846 us; speedup vs baseline: 1.0737x; 1.0102x over previous
//
#include <hip/hip_runtime.h>
#include <hip/hip_bf16.h>

// Problem constants
#define B_ 8
#define S_ 4096
#define H_ 512

using short8 = __attribute__((ext_vector_type(8))) short;
using f32x4  = __attribute__((ext_vector_type(4))) float;

// ---------- helpers ----------
__device__ __forceinline__ float bf2f(unsigned u16) {
    return __uint_as_float(u16 << 16);
}
__device__ __forceinline__ unsigned pk2bf(float x, float y) {
    __hip_bfloat162 h = __float22bfloat162_rn(make_float2(x, y));  // v_cvt_pk_bf16_f32
    return *reinterpret_cast<unsigned*>(&h);
}
__device__ __forceinline__ float softplus_f(float x) {
    float sp = __logf(1.0f + __expf(x));
    return x > 15.0f ? x : sp;
}

// async global->LDS, 16B per lane; LDS dest = wave-uniform base + lane*16
typedef __attribute__((address_space(1))) void* gbl_ptr_t;
typedef __attribute__((address_space(3))) void* lds_ptr_t;
__device__ __forceinline__ void gload_lds16(const void* g, void* l) {
    __builtin_amdgcn_global_load_lds((gbl_ptr_t)g, (lds_ptr_t)l, 16, 0, 0);
}

// raw barrier (no vmcnt/lgkmcnt drain) with compiler memory fences
#define BAR() do { asm volatile("" ::: "memory"); \
                   __builtin_amdgcn_s_barrier(); \
                   asm volatile("" ::: "memory"); } while (0)

// ---------- Pass 1: one-shot fp32 -> bf16 conversion (round-8, contiguous) ----
#define ASZ4 4194304u   // A float4 count
#define TOT4 4325376u   // A + W float4 count

__global__ __launch_bounds__(256)
void convert_bf16(const float* __restrict__ A, const float* __restrict__ Wm,
                  uint2* __restrict__ dst) {
    for (unsigned i = blockIdx.x * 256u + threadIdx.x; i < TOT4; i += 2048u * 256u) {
        const float4* p = (i < ASZ4) ? ((const float4*)A) + i
                                     : ((const float4*)Wm) + (i - ASZ4);
        const float4 v = *p;
        uint2 o;
        o.x = pk2bf(v.x, v.y);
        o.y = pk2bf(v.z, v.w);
        dst[i] = o;
    }
}

// ---------- Pass 2: 256x256 bf16 GEMM, KS=32 4-slot ring, DEPTH-3 lookahead --
// Plateau diagnosis (r4/r6/r9/r10 all ~58 us): ~800 cyc of exposed L3/first-
// touch latency + barrier convoy per wait-point; every prior variant had
// issue-to-wait distance of ONE compute phase (~310-620 cyc) < load latency
// (~700-900). This kernel is r10's VERIFIED geometry re-indexed into a 4-slot
// K-slice ring: STAGE(g+3) at slice-g start -> lookahead = 3 compute phases
// (~930+ cyc >= latency); steady vmcnt(12) = 16 outstanding, retire exactly
// slice g's 4 loads; drain 8->4->0. Slot-reuse: STAGE(g+3) overwrites slot
// (g-1)&3, whose readers finished before slice-(g-1)'s end barrier (2 barriers
// ago). LDS = 4 slots x (A 16 KB + B 16 KB) = 128 KB DYNAMIC (launch-proven
// in r10; rounds-2/3 crashes were >64 KB STATIC).
// Staging/read swizzle (r10-verified): slot granule g holds source k-granule
// g ^ ((row>>1)&3); staging source offset (lane&3)^((q>>1)&3), q=lane>>2;
// read slot l4 ^ ((l15>>1)&3). 2-way bank aliasing = free (r10: conflicts 0).
#define TM 256
#define TN 256
#define KS 32

__global__ __launch_bounds__(512, 2)
void gemm_softplus(const unsigned short* __restrict__ Ab,
                   const unsigned short* __restrict__ Wb,
                   const float* __restrict__ bias,
                   unsigned* __restrict__ QR) {
    extern __shared__ __align__(16) unsigned short smem[];
    unsigned short* Asm = smem;           // [4][8192] elems = 64 KB
    unsigned short* Bsm = smem + 32768;   // [4][8192] elems = 64 KB

    // XCD-chunked swizzle: 512 blocks = 8 XCD * 64; 4 logical-consecutive
    // blocks share bm (A strip) -> one XCD (measured FETCH ~25 MB).
    const int bid     = blockIdx.x;
    const int logical = (bid & 7) * 64 + (bid >> 3);
    const int bm = logical >> 2;     // 0..127
    const int bn = logical & 3;      // 0..3

    const int t      = threadIdx.x;
    const int wave   = t >> 6;       // 0..7
    const int lane   = t & 63;
    const int wave_m = wave >> 2;    // 0..1
    const int wave_n = wave & 3;     // 0..3
    const int wm  = wave_m * 128;
    const int wn  = wave_n * 64;
    const int l15 = lane & 15;
    const int l4  = lane >> 4;

    const int m0 = bm * TM;

    // ---- staging geometry (r10-verified) ----
    const int q_  = lane >> 2;                       // 0..15
    const int g_  = lane & 3;
    const int sgo = (g_ ^ ((q_ >> 1) & 3)) * 8;      // swizzled source k offset
    const int row0 = wave * 16 + q_;                 // issue-0 row (0..127)
    // B tile row -> W row (256 rows, 32-row q/r groups; r9/r10-verified):
    // n(row) = bn*128 + (row>>6)*32 + (row&31) + 512*((row>>5)&1)
    const int nr0 = bn * 128 + ((row0 >> 6) << 5) + (row0 & 31) + (((row0 >> 5) & 1) << 9);
    const unsigned short* agA0 = Ab + (size_t)(m0 + row0) * 512 + sgo;
    const unsigned short* agA1 = agA0 + (size_t)128 * 512;   // e=1: A rows +128
    const unsigned short* bgB0 = Wb + (size_t)nr0 * 512 + sgo;
    const unsigned short* bgB1 = bgB0 + (size_t)64 * 512;    // e=1: n(row+128)=n+64
    const int sdw = wave * 512;    // LDS dest elems within slot; +4096 for e=1

    // ---- ds_read geometry (r10-verified) ----
    const int gsw  = (l4 ^ ((l15 >> 1) & 3)) * 8;
    const int aoff = (wm + l15) * 32 + gsw;   // + i*512 per fragment
    const int boff = (wn + l15) * 32 + gsw;   // + j*512

    f32x4 acc[8][4] = {};

#define STAGE(s) do { \
    const int _kc = (s) * KS; \
    const int _sl = ((s) & 3) * 8192; \
    gload_lds16(agA0 + _kc, Asm + _sl + sdw); \
    gload_lds16(agA1 + _kc, Asm + _sl + sdw + 4096); \
    gload_lds16(bgB0 + _kc, Bsm + _sl + sdw); \
    gload_lds16(bgB1 + _kc, Bsm + _sl + sdw + 4096); \
} while (0)

#define MMA16(ibase) do { \
    __builtin_amdgcn_s_setprio(1); \
    _Pragma("unroll") for (int ii = 0; ii < 4; ++ii) \
    _Pragma("unroll") for (int jj = 0; jj < 4; ++jj) \
        acc[(ibase) + ii][jj] = __builtin_amdgcn_mfma_f32_16x16x32_bf16( \
            af[ii], bf[jj], acc[(ibase) + ii][jj], 0, 0, 0); \
    __builtin_amdgcn_s_setprio(0); \
} while (0)

// Per slice: STAGE(g+3) -> counted vmcnt (retires exactly slice g's 4 loads;
// 12 = 3 slices stay in flight) -> barrier (all waves' slice-g loads landed)
// -> 12 ds_read_b128 + 32 MFMA -> end barrier (licenses slot reuse).
#define SLICE(g, VMN, DOSTG) do { \
    const unsigned short* _a = Asm + ((g) & 3) * 8192; \
    const unsigned short* _b = Bsm + ((g) & 3) * 8192; \
    if (DOSTG) STAGE((g) + 3); \
    asm volatile("s_waitcnt vmcnt(" #VMN ")" ::: "memory"); \
    BAR(); \
    short8 af[4], bf[4]; \
    _Pragma("unroll") for (int jj = 0; jj < 4; ++jj) \
        bf[jj] = *(const short8*)(_b + boff + jj * 512); \
    _Pragma("unroll") for (int ii = 0; ii < 4; ++ii) \
        af[ii] = *(const short8*)(_a + aoff + ii * 512); \
    MMA16(0); \
    _Pragma("unroll") for (int ii = 0; ii < 4; ++ii) \
        af[ii] = *(const short8*)(_a + aoff + (ii + 4) * 512); \
    MMA16(4); \
    BAR(); \
} while (0)

    // prologue: fill slots 0..2 (12 loads in flight per wave)
    STAGE(0); STAGE(1); STAGE(2);

    // steady state: 13 slices with 3-slice lookahead, vmcnt(12)
    for (int g = 0; g < 13; ++g) SLICE(g, 12, 1);
    // tail: drain 12 -> 8 -> 4 -> 0
    SLICE(13, 8, 0);
    SLICE(14, 4, 0);
    SLICE(15, 0, 0);

#undef SLICE
#undef MMA16
#undef STAGE

    // epilogue (r9/r10-verified): bias + softplus, packed {q,r} 4B stores
#pragma unroll
    for (int j = 0; j < 2; ++j) {
        const int h  = bn * 128 + (wn >> 1) + j * 16 + l15;  // 0..511
        const float bq = bias[h];
        const float br = bias[h + 512];
#pragma unroll
        for (int i = 0; i < 8; ++i) {
            const int mb = m0 + wm + i * 16 + l4 * 4;
#pragma unroll
            for (int r = 0; r < 4; ++r) {
                const float qv = softplus_f(acc[i][j][r] + bq);
                const float rv = softplus_f(acc[i][j + 2][r] + br);
                QR[(size_t)(mb + r) * 512 + h] = pk2bf(qv, rv);
            }
        }
    }
}

// ---------- Pass 3: chunked Kalman scan ----------
// CHUNK 128 -> 256 (WARM stays 64): read amplification 1.5x -> 1.25x
// (saves ~32 MB of HBM reads). Every output position now has >= the history
// it had at CHUNK=128 (positions 128..255 of each chunk gain 192+ steps of
// history vs 64 before) -> accuracy can only improve. Grid = 2 h-halves x
// 8 b x 16 chunks = 256 blocks of 256 threads (exactly 1 block/CU, 1 round);
// ng in {32, 40}, both multiples of 8 -> unguarded COMP; depth-4 prefetch
// (64 loads/thread in flight) provides the MLP at 1 wave/SIMD.
#define CHUNK 256
#define WARM 64

__global__ __launch_bounds__(256, 2)
void kalman_scan(const float* __restrict__ z,
                 const unsigned* __restrict__ QR,
                 float* __restrict__ out) {
    const int t     = threadIdx.x;
    const int hb    = blockIdx.x & 1;
    const int b     = (blockIdx.x >> 1) & 7;
    const int chunk = blockIdx.x >> 4;          // 0..15
    const int h     = hb * 256 + t;             // 0..511
    const int s0    = chunk << 8;               // chunk*256
    const int sw    = (chunk == 0) ? 0 : (s0 - WARM);
    const size_t base = ((size_t)(b * S_ + sw)) * 512 + h;

    const float*    zp  = z + base;             // stride 512 floats / step
    const unsigned* qrp = (const unsigned*)QR + base;
    float*          op  = out + base;

    const int ng    = ((s0 + CHUNK) - sw) >> 3;   // 32 (chunk 0) or 40
    const int skipg = (s0 - sw) >> 3;             // 0 or 8

    float    Z0[8], Z1[8], Z2[8], Z3[8], Z4[8], Z5[8], Z6[8], Z7[8];
    unsigned Q0[8], Q1[8], Q2[8], Q3[8], Q4[8], Q5[8], Q6[8], Q7[8];

#define LOADG(g, Zb, Qb) { const int _o = (g) * 8;                          \
    _Pragma("unroll") for (int u = 0; u < 8; ++u) {                         \
        Zb[u] = zp[(size_t)(_o + u) * 512]; Qb[u] = qrp[(size_t)(_o + u) * 512]; } }

#define COMP(g, Zb, Qb) { const int _o = (g) * 8; const bool _st = (g) >= skipg; \
    _Pragma("unroll") for (int u = 0; u < 8; ++u) {                         \
        const float q  = bf2f(Qb[u] & 0xffffu);                             \
        const float r  = bf2f(Qb[u] >> 16);                                 \
        const float Pp = P + q, rr = r + 1e-6f;                             \
        const float K  = Pp * __builtin_amdgcn_rcpf(Pp + rr);               \
        state = fmaf(K, Zb[u] - state, state); P = rr * K;                  \
        if (_st) op[(size_t)(_o + u) * 512] = state; } }

    LOADG(0, Z0, Q0); LOADG(1, Z1, Q1); LOADG(2, Z2, Q2); LOADG(3, Z3, Q3);

    float state = Z0[0];   // state init = z[sw]
    float P = 0.1f;

    for (int g = 0; g < ng; g += 8) {
        if (g + 4  < ng) LOADG(g + 4,  Z4, Q4); COMP(g,     Z0, Q0);
        if (g + 5  < ng) LOADG(g + 5,  Z5, Q5); COMP(g + 1, Z1, Q1);
        if (g + 6  < ng) LOADG(g + 6,  Z6, Q6); COMP(g + 2, Z2, Q2);
        if (g + 7  < ng) LOADG(g + 7,  Z7, Q7); COMP(g + 3, Z3, Q3);
        if (g + 8  < ng) LOADG(g + 8,  Z0, Q0); COMP(g + 4, Z4, Q4);
        if (g + 9  < ng) LOADG(g + 9,  Z1, Q1); COMP(g + 5, Z5, Q5);
        if (g + 10 < ng) LOADG(g + 10, Z2, Q2); COMP(g + 6, Z6, Q6);
        if (g + 11 < ng) LOADG(g + 11, Z3, Q3); COMP(g + 7, Z7, Q7);
    }
#undef LOADG
#undef COMP
}

extern "C" void kernel_launch(void* const* d_in, const int* in_sizes, int n_in,
                              void* d_out, int out_size, void* d_ws, size_t ws_size,
                              hipStream_t stream) {
    const float* lstm = (const float*)d_in[0];   // (8,4096,512) fp32
    const float* Wm   = (const float*)d_in[1];   // (1024,512)  fp32
    const float* bias = (const float*)d_in[2];   // (1024,)     fp32

    unsigned* QRw = (unsigned*)d_ws;             // packed {q,r} bf16x2, 64 MB

    // d_out (64 MB) is dead until the scan writes it -> bf16 scratch:
    // Ab = 32 MB at offset 0, Wb = 1 MB at offset 32 MB (contiguous).
    unsigned short* Abf = (unsigned short*)d_out;
    unsigned short* Wbf = (unsigned short*)((char*)d_out + (32u << 20));

    // enable 128 KB dynamic LDS for the GEMM (host-side, graph-capture-safe)
    static bool lds_set = false;
    if (!lds_set) {
        hipFuncSetAttribute(reinterpret_cast<const void*>(&gemm_softplus),
                            hipFuncAttributeMaxDynamicSharedMemorySize, 131072);
        lds_set = true;
    }

    hipLaunchKernelGGL(convert_bf16, dim3(2048), dim3(256), 0, stream,
                       lstm, Wm, (uint2*)Abf);

    // 128 M-tiles x 4 N-tiles = 512 blocks of 512 threads, 128 KB dynamic LDS
    hipLaunchKernelGGL(gemm_softplus, dim3(512), dim3(512), 131072, stream,
                       Abf, Wbf, bias, QRw);

    // 2 h-halves * 8 batches * 16 chunks = 256 blocks of 256 threads
    hipLaunchKernelGGL(kalman_scan, dim3(256), dim3(256), 0, stream,
                       lstm, QRw, (float*)d_out);
}